// Round 18
// baseline (80.798 us; speedup 1.0000x reference)
//
#include <hip/hip_runtime.h>

typedef _Float16 f16;
typedef f16 f16x8 __attribute__((ext_vector_type(8)));
typedef f16 f16x4 __attribute__((ext_vector_type(4)));
typedef __fp16 fp16x2 __attribute__((ext_vector_type(2)));
typedef float f32x4 __attribute__((ext_vector_type(4)));
typedef float f32x16 __attribute__((ext_vector_type(16)));
typedef unsigned int u32;

#define NTOK 4096

// async global->LDS, 16B per lane; dest MUST be wave-uniform (HW: base + lane*16)
#define GLL(gsrc, ldst) \
  __builtin_amdgcn_global_load_lds( \
      (const __attribute__((address_space(1))) void*)(gsrc), \
      (__attribute__((address_space(3))) void*)(ldst), 16, 0, 0)

// ---------------- f32 -> f16 convert (x | w_qkv | w_out) ----------------
__global__ __launch_bounds__(256) void k_cvt(
    const float* __restrict__ x, const float* __restrict__ wq,
    const float* __restrict__ wo,
    f16* __restrict__ xb, f16* __restrict__ wqb, f16* __restrict__ wob)
{
  const int bx = blockIdx.x;
  const float* src; f16* dst; int off;
  if (bx < 2048)      { src = x;  dst = xb;  off = bx * 1024; }
  else if (bx < 2240) { src = wq; dst = wqb; off = (bx - 2048) * 1024; }
  else                { src = wo; dst = wob; off = (bx - 2240) * 1024; }
  const int i = off + threadIdx.x * 4;
  float4 f = *(const float4*)(src + i);
  f16x4 h;
  h[0] = (f16)f.x; h[1] = (f16)f.y; h[2] = (f16)f.z; h[3] = (f16)f.w;
  *(f16x4*)(dst + i) = h;
}

// ---------------- generic C = A[M,K] * W[NC,K]^T MFMA GEMM (proven) ----------
// mode 0: QKV epilogue -> scatter Qb/Kb/Vtb + fused norm partials
// mode 1: out epilogue -> d_out f32 + bias
// XCD-bijective block swizzle (T1, m204): each XCD owns a contiguous by-chunk
// so A-panels are filled into exactly one XCD's L2 (grid sizes are %8==0).
__global__ __launch_bounds__(256) void k_gemm(
    const f16* __restrict__ A, const f16* __restrict__ W,
    int K, int mode,
    f16* __restrict__ Qb, f16* __restrict__ Kb, f16* __restrict__ Vtb,
    float* __restrict__ outF, const float* __restrict__ bias,
    float* __restrict__ partQ, float* __restrict__ partK)
{
  __shared__ f16 Al[64 * 40];
  __shared__ f16 Wl[64 * 40];
  __shared__ float redl[4][64];
  const int t = threadIdx.x;
  const int w = t >> 6, l = t & 63;
  const int lrow = l & 15, lk = l >> 4;
  // bijective XCD swizzle: lin -> orig = (lin%8)*(nwg/8) + lin/8
  const int lin = blockIdx.x + gridDim.x * blockIdx.y;
  const int cpx = (gridDim.x * gridDim.y) >> 3;
  const int orig = (lin & 7) * cpx + (lin >> 3);
  const int bxs = orig % gridDim.x, bys = orig / gridDim.x;
  const int m0 = bys * 64, nc0 = bxs * 64;
  f32x4 acc[4] = {};
  const int srow = t >> 2, sseg = t & 3;
  for (int k0 = 0; k0 < K; k0 += 32) {
    __syncthreads();
    f16x8 av = *(const f16x8*)(A + (size_t)(m0 + srow) * K + k0 + sseg * 8);
    f16x8 wv = *(const f16x8*)(W + (size_t)(nc0 + srow) * K + k0 + sseg * 8);
    *(f16x8*)(Al + srow * 40 + sseg * 8) = av;
    *(f16x8*)(Wl + srow * 40 + sseg * 8) = wv;
    __syncthreads();
    f16x8 af = *(const f16x8*)(Al + (w * 16 + lrow) * 40 + lk * 8);
#pragma unroll
    for (int ct = 0; ct < 4; ++ct) {
      f16x8 bf = *(const f16x8*)(Wl + (ct * 16 + lrow) * 40 + lk * 8);
      acc[ct] = __builtin_amdgcn_mfma_f32_16x16x32_f16(af, bf, acc[ct], 0, 0, 0);
    }
  }
  const int nb = m0 + w * 16 + lk * 4;
  if (mode == 0) {
    const int b = nb >> 12, n = nb & 4095;
#pragma unroll
    for (int ct = 0; ct < 4; ++ct) {
      int gc = nc0 + ct * 16 + lrow;
      int s = gc >> 8, h = (gc >> 6) & 3, dd = gc & 63;
      int bh = b * 4 + h;
      if (s == 2) {
        f16x4 v;
#pragma unroll
        for (int j = 0; j < 4; ++j) v[j] = (f16)acc[ct][j];
        *(f16x4*)(Vtb + ((size_t)bh * 64 + dd) * 4096 + n) = v;
      } else {
        f16* dst = (s == 0) ? Qb : Kb;
#pragma unroll
        for (int j = 0; j < 4; ++j)
          dst[((size_t)bh * 4096 + n + j) * 64 + dd] = (f16)acc[ct][j];
      }
    }
    // fused per-channel squared-sum partials (over this block's 64 tokens)
    if (nc0 < 512) {
#pragma unroll
      for (int ct = 0; ct < 4; ++ct) {
        float v = acc[ct][0] * acc[ct][0] + acc[ct][1] * acc[ct][1]
                + acc[ct][2] * acc[ct][2] + acc[ct][3] * acc[ct][3];
        v += __shfl_xor(v, 16, 64);
        v += __shfl_xor(v, 32, 64);
        if (lk == 0) redl[w][ct * 16 + lrow] = v;
      }
      __syncthreads();
      if (t < 64) {
        float sq = redl[0][t] + redl[1][t] + redl[2][t] + redl[3][t];
        const int s = nc0 >> 8, h2 = (nc0 >> 6) & 3;
        const int b2 = m0 >> 12, mb = (m0 >> 6) & 63;
        float* dst = (s == 0) ? partQ : partK;
        dst[((b2 * 4 + h2) * 64 + mb) * 64 + t] = sq;
      }
    }
  } else {
#pragma unroll
    for (int ct = 0; ct < 4; ++ct) {
      int gc = nc0 + ct * 16 + lrow;
      float bv = bias[gc];
#pragma unroll
      for (int j = 0; j < 4; ++j)
        outF[(size_t)(nb + j) * 256 + gc] = acc[ct][j] + bv;
    }
  }
}

// ---------------- flash attention v6 + inline cq (norm2 folded in) -----------
// QBLK=64, 512 blocks, 2 blocks/CU, 8 waves = 4 ks x 2 qh; K,V LDS dbuf via GLL.
// Prologue: each block computes its bh's c[dd] = temp*log2e/(|q||k|) from the
// gemm partials (L2-hot, two-stage LDS reduce into Lsh[0..63]).
__device__ inline void plane_swap(u32& a, u32& b) {
  asm volatile("v_permlane32_swap_b32 %0, %1" : "+v"(a), "+v"(b));
}

__global__ __launch_bounds__(512, 4) void k_flash6(
    const f16* __restrict__ Qb, const f16* __restrict__ Kb,
    const f16* __restrict__ Vtb,
    const float* __restrict__ partQ, const float* __restrict__ partK,
    const float* __restrict__ temp,
    f16* __restrict__ Y)
{
  __shared__ f16 KVl[32768];    // 2 x (K 128x64 | V 64x128) = 64KB; aliased pre/post
  __shared__ float Lsh[256];    // pre-loop: cq[0..63]; epilogue: [w][32 q] row sums
  const int t = threadIdx.x, w = t >> 6, l = t & 63;
  const int r = l & 31, hi = l >> 5;
  const int ks = w >> 1, qh = w & 1;
  const int r7 = r & 7;
  // XCD-bijective swizzle: 512 blocks, each XCD owns one (b,h)
  int nb2 = (blockIdx.x & 7) * 64 + (blockIdx.x >> 3);
  const int bh = nb2 >> 6, qt = nb2 & 63;
  const size_t base = (size_t)bh * NTOK * 64;
  // ---- inline cq: Lsh[dd] = temp[h]*log2e / (|q_dd| * |k_dd|) ----
  {
    float* red = (float*)KVl;            // 2 x 8 parts x 64 dd (4KB alias)
    const int dd = t & 63, part = t >> 6;
    const float* pq = partQ + (size_t)bh * 4096 + part * 512 + dd;
    const float* pk = partK + (size_t)bh * 4096 + part * 512 + dd;
    float sq = 0.f, sk = 0.f;
#pragma unroll
    for (int s = 0; s < 8; ++s) { sq += pq[s * 64]; sk += pk[s * 64]; }
    red[part * 64 + dd] = sq;
    red[512 + part * 64 + dd] = sk;
    __syncthreads();
    if (t < 64) {
      float sq2 = 0.f, sk2 = 0.f;
#pragma unroll
      for (int s = 0; s < 8; ++s) { sq2 += red[s * 64 + t]; sk2 += red[512 + s * 64 + t]; }
      Lsh[t] = temp[bh & 3] * 1.4426950408889634f /
               (fmaxf(sqrtf(sq2), 1e-12f) * fmaxf(sqrtf(sk2), 1e-12f));
    }
    __syncthreads();
  }
  // Q fragments (32 q), scaled by cq (LDS broadcast, f32 mul)
  f16x8 qf0, qf1, qf2, qf3;
  {
    const f16* qp = Qb + base + (size_t)(qt * 64 + qh * 32 + r) * 64 + hi * 8;
#define QLOAD(QF, CH) { f16x8 tmp = *(const f16x8*)(qp + (CH) * 16); \
    _Pragma("unroll") for (int j = 0; j < 8; ++j) \
      QF[j] = (f16)((float)tmp[j] * Lsh[(CH) * 16 + hi * 8 + j]); }
    QLOAD(qf0, 0) QLOAD(qf1, 1) QLOAD(qf2, 2) QLOAD(qf3, 3)
#undef QLOAD
  }
  // staging source pointers (pre-swizzled global addresses, rule #21)
  const f16* srcK = Kb + base + (size_t)(w * 8 + (l >> 3)) * 64 + ((l & 7) ^ (l >> 3)) * 8;
  const int vrow = w * 4 + (l >> 4);
  const f16* srcV = Vtb + base + (size_t)vrow * 4096 + ((l & 15) ^ (vrow & 7)) * 8;
  const int dK = w * 512;
  const int dV = 8192 + w * 512;
#define STAGE(cur, tile) { \
    const f16* sk_ = srcK + (size_t)(tile) * 8192; \
    const f16* sv_ = srcV + (tile) * 128; \
    GLL(sk_,          KVl + (cur) * 16384 + dK); \
    GLL(sk_ + 4096,   KVl + (cur) * 16384 + dK + 4096); \
    GLL(sv_,          KVl + (cur) * 16384 + dV); \
    GLL(sv_ + 131072, KVl + (cur) * 16384 + dV + 4096); }
  // fragment read offsets (f16 units, constant across stages)
  const int kro = (ks * 32 + r) * 64;
  const int kc0 = ((0 + hi) ^ r7) * 8, kc1 = ((2 + hi) ^ r7) * 8;
  const int kc2 = ((4 + hi) ^ r7) * 8, kc3 = ((6 + hi) ^ r7) * 8;
  const int vb0 = 8192 + r * 128, vb1 = 8192 + (32 + r) * 128;
  const int vc0 = ((ks * 4 + 0 + hi) ^ r7) * 8, vc1 = ((ks * 4 + 2 + hi) ^ r7) * 8;

  f32x16 oacc0 = {}, oacc1 = {};
  float lsw = 0.f;
  __syncthreads();   // cq reads done; KVl free for staging
  STAGE(0, 0);
  __syncthreads();
  for (int tl = 0; tl < 32; ++tl) {
    const int cur = tl & 1;
    const f16* Bb = KVl + cur * 16384;
    f16x8 kf0 = *(const f16x8*)(Bb + kro + kc0);
    f16x8 kf1 = *(const f16x8*)(Bb + kro + kc1);
    f16x8 kf2 = *(const f16x8*)(Bb + kro + kc2);
    f16x8 kf3 = *(const f16x8*)(Bb + kro + kc3);
    f16x8 vf0 = *(const f16x8*)(Bb + vb0 + vc0);
    f16x8 vf1 = *(const f16x8*)(Bb + vb0 + vc1);
    f16x8 vf2 = *(const f16x8*)(Bb + vb1 + vc0);
    f16x8 vf3 = *(const f16x8*)(Bb + vb1 + vc1);
    if (tl < 31) STAGE(cur ^ 1, tl + 1);
    // QK^T
    f32x16 sacc = {};
    __builtin_amdgcn_s_setprio(1);
    sacc = __builtin_amdgcn_mfma_f32_32x32x16_f16(kf0, qf0, sacc, 0, 0, 0);
    sacc = __builtin_amdgcn_mfma_f32_32x32x16_f16(kf1, qf1, sacc, 0, 0, 0);
    sacc = __builtin_amdgcn_mfma_f32_32x32x16_f16(kf2, qf2, sacc, 0, 0, 0);
    sacc = __builtin_amdgcn_mfma_f32_32x32x16_f16(kf3, qf3, sacc, 0, 0, 0);
    __builtin_amdgcn_s_setprio(0);
    // softmax in-register: exp2, pack, permlane redistribute
    u32 Dw[8];
#pragma unroll
    for (int u = 0; u < 4; ++u) {
#pragma unroll
      for (int v = 0; v < 2; ++v) {
        float a  = __builtin_amdgcn_exp2f(sacc[u * 4 + v * 2]);
        float b2 = __builtin_amdgcn_exp2f(sacc[u * 4 + v * 2 + 1]);
        lsw += a + b2;
        union { fp16x2 h; u32 u; } cv;
        cv.h = __builtin_amdgcn_cvt_pkrtz(a, b2);
        Dw[u * 2 + v] = cv.u;
      }
    }
    plane_swap(Dw[0], Dw[2]);
    plane_swap(Dw[1], Dw[3]);
    plane_swap(Dw[4], Dw[6]);
    plane_swap(Dw[5], Dw[7]);
    union { f16x8 v; u32 d[4]; } p0, p1;
    p0.d[0] = Dw[0]; p0.d[1] = Dw[1]; p0.d[2] = Dw[2]; p0.d[3] = Dw[3];
    p1.d[0] = Dw[4]; p1.d[1] = Dw[5]; p1.d[2] = Dw[6]; p1.d[3] = Dw[7];
    // PV
    __builtin_amdgcn_s_setprio(1);
    oacc0 = __builtin_amdgcn_mfma_f32_32x32x16_f16(p0.v, vf0, oacc0, 0, 0, 0);
    oacc0 = __builtin_amdgcn_mfma_f32_32x32x16_f16(p1.v, vf1, oacc0, 0, 0, 0);
    oacc1 = __builtin_amdgcn_mfma_f32_32x32x16_f16(p0.v, vf2, oacc1, 0, 0, 0);
    oacc1 = __builtin_amdgcn_mfma_f32_32x32x16_f16(p1.v, vf3, oacc1, 0, 0, 0);
    __builtin_amdgcn_s_setprio(0);
    __syncthreads();
  }
#undef STAGE
  // ---- epilogue: combine 4 key-slice partials via LDS (alias of KVl) ----
  lsw += __shfl_xor(lsw, 32, 64);
  if (hi == 0) Lsh[w * 32 + r] = lsw;
#pragma unroll
  for (int dt = 0; dt < 2; ++dt) {
    f16* orow = KVl + w * 2048 + (dt * 32 + r) * 32;
    const f32x16& oa = dt ? oacc1 : oacc0;
#pragma unroll
    for (int u = 0; u < 4; ++u) {
      f16x4 h4;
      h4[0] = (f16)oa[u * 4 + 0]; h4[1] = (f16)oa[u * 4 + 1];
      h4[2] = (f16)oa[u * 4 + 2]; h4[3] = (f16)oa[u * 4 + 3];
      *(f16x4*)(orow + ((u ^ (r & 3)) * 8) + hi * 4) = h4;
    }
  }
  __syncthreads();
  // combine: wave w = (s2 q-16-group-pair, dt2 dd-half, qh2 q-half)
  const int s2 = w >> 2, dt2 = (w >> 1) & 1, qh2 = w & 1;
  const int g = s2 * 2 + hi;    // q 8-group within 32-half
  const int b = bh >> 2, h = bh & 3;
  float accv[8] = {}, denv[8] = {};
#pragma unroll
  for (int ksl = 0; ksl < 4; ++ksl) {
    const int wp = ksl * 2 + qh2;
    f16x8 rd = *(const f16x8*)(KVl + wp * 2048 + (dt2 * 32 + r) * 32 + ((g ^ (r & 3)) * 8));
    f32x4 la = *(const f32x4*)(Lsh + wp * 32 + g * 8);
    f32x4 lb = *(const f32x4*)(Lsh + wp * 32 + g * 8 + 4);
#pragma unroll
    for (int j = 0; j < 4; ++j) {
      accv[j]     += (float)rd[j];
      accv[4 + j] += (float)rd[4 + j];
      denv[j]     += la[j];
      denv[4 + j] += lb[j];
    }
  }
  const int ng = qt * 64 + qh2 * 32 + g * 8;
  const int np = (dt2 * 32 + r) * 64 + h * 16 + (ng >> 8);
  const int cp_ = ng & 255;
  f16x8 yv;
#pragma unroll
  for (int j = 0; j < 8; ++j) yv[j] = (f16)(accv[j] / denv[j]);
  *(f16x8*)(Y + ((size_t)b * 4096 + np) * 256 + cp_) = yv;
}

extern "C" void kernel_launch(void* const* d_in, const int* in_sizes, int n_in,
                              void* d_out, int out_size, void* d_ws, size_t ws_size,
                              hipStream_t stream)
{
  const float* x     = (const float*)d_in[0];   // [2,4096,256]
  const float* w_qkv = (const float*)d_in[1];   // [768,256]
  const float* w_out = (const float*)d_in[2];   // [256,256]
  const float* b_out = (const float*)d_in[3];   // [256]
  const float* temp  = (const float*)d_in[4];   // [4,1,1]

  char* ws = (char*)d_ws;
  f16*   xb    = (f16*)(ws);                                  // 4MB
  f16*   wqkvb = (f16*)(ws + 4 * 1024 * 1024);
  f16*   woutb = (f16*)(ws + 4 * 1024 * 1024 + 512 * 1024);
  f16*   Qb    = (f16*)(ws + 5  * 1024 * 1024);               // [8][4096][64]
  f16*   Kb    = (f16*)(ws + 9  * 1024 * 1024);
  f16*   Vtb   = (f16*)(ws + 13 * 1024 * 1024);               // [8][64][4096]
  float* partQ = (float*)(ws + 17 * 1024 * 1024 + 8192);      // 128KB
  float* partK = (float*)(ws + 17 * 1024 * 1024 + 8192 + 131072);
  f16*   Y     = (f16*)(ws + 18 * 1024 * 1024);               // [2][4096][256]
  float* outF  = (float*)d_out;

  k_cvt<<<2304, 256, 0, stream>>>(x, w_qkv, w_out, xb, wqkvb, woutb);
  k_gemm<<<dim3(12, 128), 256, 0, stream>>>(xb, wqkvb, 256, 0, Qb, Kb, Vtb,
                                            nullptr, nullptr, partQ, partK);
  k_flash6<<<512, 512, 0, stream>>>(Qb, Kb, Vtb, partQ, partK, temp, Y);
  k_gemm<<<dim3(4, 128), 256, 0, stream>>>(Y, woutb, 256, 1, nullptr, nullptr, nullptr,
                                           outF, b_out, nullptr, nullptr);
}

// Round 19
// 79.403 us; speedup vs baseline: 1.0176x; 1.0176x over previous
//
#include <hip/hip_runtime.h>

typedef _Float16 f16;
typedef f16 f16x8 __attribute__((ext_vector_type(8)));
typedef f16 f16x4 __attribute__((ext_vector_type(4)));
typedef __fp16 fp16x2 __attribute__((ext_vector_type(2)));
typedef float f32x4 __attribute__((ext_vector_type(4)));
typedef float f32x16 __attribute__((ext_vector_type(16)));
typedef unsigned int u32;

#define NTOK 4096

// async global->LDS, 16B per lane; dest MUST be wave-uniform (HW: base + lane*16)
#define GLL(gsrc, ldst) \
  __builtin_amdgcn_global_load_lds( \
      (const __attribute__((address_space(1))) void*)(gsrc), \
      (__attribute__((address_space(3))) void*)(ldst), 16, 0, 0)

// ---------------- f32 -> f16 convert (x | w_qkv | w_out) ----------------
__global__ __launch_bounds__(256) void k_cvt(
    const float* __restrict__ x, const float* __restrict__ wq,
    const float* __restrict__ wo,
    f16* __restrict__ xb, f16* __restrict__ wqb, f16* __restrict__ wob)
{
  const int bx = blockIdx.x;
  const float* src; f16* dst; int off;
  if (bx < 2048)      { src = x;  dst = xb;  off = bx * 1024; }
  else if (bx < 2240) { src = wq; dst = wqb; off = (bx - 2048) * 1024; }
  else                { src = wo; dst = wob; off = (bx - 2240) * 1024; }
  const int i = off + threadIdx.x * 4;
  float4 f = *(const float4*)(src + i);
  f16x4 h;
  h[0] = (f16)f.x; h[1] = (f16)f.y; h[2] = (f16)f.z; h[3] = (f16)f.w;
  *(f16x4*)(dst + i) = h;
}

// ---------------- generic C = A[M,K] * W[NC,K]^T MFMA GEMM (proven) ----------
// mode 0: QKV epilogue -> scatter Qb/Kb/Vtb + fused norm partials
// mode 1: out epilogue -> d_out f32 + bias
__global__ __launch_bounds__(256) void k_gemm(
    const f16* __restrict__ A, const f16* __restrict__ W,
    int K, int mode,
    f16* __restrict__ Qb, f16* __restrict__ Kb, f16* __restrict__ Vtb,
    float* __restrict__ outF, const float* __restrict__ bias,
    float* __restrict__ partQ, float* __restrict__ partK)
{
  __shared__ f16 Al[64 * 40];
  __shared__ f16 Wl[64 * 40];
  __shared__ float redl[4][64];
  const int t = threadIdx.x;
  const int w = t >> 6, l = t & 63;
  const int lrow = l & 15, lk = l >> 4;
  const int m0 = blockIdx.y * 64, nc0 = blockIdx.x * 64;
  f32x4 acc[4] = {};
  const int srow = t >> 2, sseg = t & 3;
  for (int k0 = 0; k0 < K; k0 += 32) {
    __syncthreads();
    f16x8 av = *(const f16x8*)(A + (size_t)(m0 + srow) * K + k0 + sseg * 8);
    f16x8 wv = *(const f16x8*)(W + (size_t)(nc0 + srow) * K + k0 + sseg * 8);
    *(f16x8*)(Al + srow * 40 + sseg * 8) = av;
    *(f16x8*)(Wl + srow * 40 + sseg * 8) = wv;
    __syncthreads();
    f16x8 af = *(const f16x8*)(Al + (w * 16 + lrow) * 40 + lk * 8);
#pragma unroll
    for (int ct = 0; ct < 4; ++ct) {
      f16x8 bf = *(const f16x8*)(Wl + (ct * 16 + lrow) * 40 + lk * 8);
      acc[ct] = __builtin_amdgcn_mfma_f32_16x16x32_f16(af, bf, acc[ct], 0, 0, 0);
    }
  }
  const int nb = m0 + w * 16 + lk * 4;
  if (mode == 0) {
    const int b = nb >> 12, n = nb & 4095;
#pragma unroll
    for (int ct = 0; ct < 4; ++ct) {
      int gc = nc0 + ct * 16 + lrow;
      int s = gc >> 8, h = (gc >> 6) & 3, dd = gc & 63;
      int bh = b * 4 + h;
      if (s == 2) {
        f16x4 v;
#pragma unroll
        for (int j = 0; j < 4; ++j) v[j] = (f16)acc[ct][j];
        *(f16x4*)(Vtb + ((size_t)bh * 64 + dd) * 4096 + n) = v;
      } else {
        f16* dst = (s == 0) ? Qb : Kb;
#pragma unroll
        for (int j = 0; j < 4; ++j)
          dst[((size_t)bh * 4096 + n + j) * 64 + dd] = (f16)acc[ct][j];
      }
    }
    // fused per-channel squared-sum partials (over this block's 64 tokens)
    if (nc0 < 512) {
#pragma unroll
      for (int ct = 0; ct < 4; ++ct) {
        float v = acc[ct][0] * acc[ct][0] + acc[ct][1] * acc[ct][1]
                + acc[ct][2] * acc[ct][2] + acc[ct][3] * acc[ct][3];
        v += __shfl_xor(v, 16, 64);
        v += __shfl_xor(v, 32, 64);
        if (lk == 0) redl[w][ct * 16 + lrow] = v;
      }
      __syncthreads();
      if (t < 64) {
        float sq = redl[0][t] + redl[1][t] + redl[2][t] + redl[3][t];
        const int s = nc0 >> 8, h2 = (nc0 >> 6) & 3;
        const int b2 = m0 >> 12, mb = (m0 >> 6) & 63;
        float* dst = (s == 0) ? partQ : partK;
        dst[((b2 * 4 + h2) * 64 + mb) * 64 + t] = sq;
      }
    }
  } else {
#pragma unroll
    for (int ct = 0; ct < 4; ++ct) {
      int gc = nc0 + ct * 16 + lrow;
      float bv = bias[gc];
#pragma unroll
      for (int j = 0; j < 4; ++j)
        outF[(size_t)(nb + j) * 256 + gc] = acc[ct][j] + bv;
    }
  }
}

// ---------------- flash attention v6 + inline cq (norm2 folded in) -----------
// QBLK=64, 512 blocks, 2 blocks/CU, 8 waves = 4 ks x 2 qh; K,V LDS dbuf via GLL.
// Prologue: each block computes its bh's c[dd] = temp*log2e/(|q||k|) from the
// gemm partials (L2-hot, two-stage LDS reduce into Lsh[0..63]).
__device__ inline void plane_swap(u32& a, u32& b) {
  asm volatile("v_permlane32_swap_b32 %0, %1" : "+v"(a), "+v"(b));
}

__global__ __launch_bounds__(512, 4) void k_flash6(
    const f16* __restrict__ Qb, const f16* __restrict__ Kb,
    const f16* __restrict__ Vtb,
    const float* __restrict__ partQ, const float* __restrict__ partK,
    const float* __restrict__ temp,
    f16* __restrict__ Y)
{
  __shared__ f16 KVl[32768];    // 2 x (K 128x64 | V 64x128) = 64KB; aliased pre/post
  __shared__ float Lsh[256];    // pre-loop: cq[0..63]; epilogue: [w][32 q] row sums
  const int t = threadIdx.x, w = t >> 6, l = t & 63;
  const int r = l & 31, hi = l >> 5;
  const int ks = w >> 1, qh = w & 1;
  const int r7 = r & 7;
  // XCD-bijective swizzle: 512 blocks, each XCD owns one (b,h)
  int nb2 = (blockIdx.x & 7) * 64 + (blockIdx.x >> 3);
  const int bh = nb2 >> 6, qt = nb2 & 63;
  const size_t base = (size_t)bh * NTOK * 64;
  // ---- inline cq: Lsh[dd] = temp[h]*log2e / (|q_dd| * |k_dd|) ----
  {
    float* red = (float*)KVl;            // 2 x 8 parts x 64 dd (4KB alias)
    const int dd = t & 63, part = t >> 6;
    const float* pq = partQ + (size_t)bh * 4096 + part * 512 + dd;
    const float* pk = partK + (size_t)bh * 4096 + part * 512 + dd;
    float sq = 0.f, sk = 0.f;
#pragma unroll
    for (int s = 0; s < 8; ++s) { sq += pq[s * 64]; sk += pk[s * 64]; }
    red[part * 64 + dd] = sq;
    red[512 + part * 64 + dd] = sk;
    __syncthreads();
    if (t < 64) {
      float sq2 = 0.f, sk2 = 0.f;
#pragma unroll
      for (int s = 0; s < 8; ++s) { sq2 += red[s * 64 + t]; sk2 += red[512 + s * 64 + t]; }
      Lsh[t] = temp[bh & 3] * 1.4426950408889634f /
               (fmaxf(sqrtf(sq2), 1e-12f) * fmaxf(sqrtf(sk2), 1e-12f));
    }
    __syncthreads();
  }
  // Q fragments (32 q), scaled by cq (LDS broadcast, f32 mul)
  f16x8 qf0, qf1, qf2, qf3;
  {
    const f16* qp = Qb + base + (size_t)(qt * 64 + qh * 32 + r) * 64 + hi * 8;
#define QLOAD(QF, CH) { f16x8 tmp = *(const f16x8*)(qp + (CH) * 16); \
    _Pragma("unroll") for (int j = 0; j < 8; ++j) \
      QF[j] = (f16)((float)tmp[j] * Lsh[(CH) * 16 + hi * 8 + j]); }
    QLOAD(qf0, 0) QLOAD(qf1, 1) QLOAD(qf2, 2) QLOAD(qf3, 3)
#undef QLOAD
  }
  // staging source pointers (pre-swizzled global addresses, rule #21)
  const f16* srcK = Kb + base + (size_t)(w * 8 + (l >> 3)) * 64 + ((l & 7) ^ (l >> 3)) * 8;
  const int vrow = w * 4 + (l >> 4);
  const f16* srcV = Vtb + base + (size_t)vrow * 4096 + ((l & 15) ^ (vrow & 7)) * 8;
  const int dK = w * 512;
  const int dV = 8192 + w * 512;
#define STAGE(cur, tile) { \
    const f16* sk_ = srcK + (size_t)(tile) * 8192; \
    const f16* sv_ = srcV + (tile) * 128; \
    GLL(sk_,          KVl + (cur) * 16384 + dK); \
    GLL(sk_ + 4096,   KVl + (cur) * 16384 + dK + 4096); \
    GLL(sv_,          KVl + (cur) * 16384 + dV); \
    GLL(sv_ + 131072, KVl + (cur) * 16384 + dV + 4096); }
  // fragment read offsets (f16 units, constant across stages)
  const int kro = (ks * 32 + r) * 64;
  const int kc0 = ((0 + hi) ^ r7) * 8, kc1 = ((2 + hi) ^ r7) * 8;
  const int kc2 = ((4 + hi) ^ r7) * 8, kc3 = ((6 + hi) ^ r7) * 8;
  const int vb0 = 8192 + r * 128, vb1 = 8192 + (32 + r) * 128;
  const int vc0 = ((ks * 4 + 0 + hi) ^ r7) * 8, vc1 = ((ks * 4 + 2 + hi) ^ r7) * 8;

  f32x16 oacc0 = {}, oacc1 = {};
  float lsw = 0.f;
  __syncthreads();   // cq reads done; KVl free for staging
  STAGE(0, 0);
  __syncthreads();
  for (int tl = 0; tl < 32; ++tl) {
    const int cur = tl & 1;
    const f16* Bb = KVl + cur * 16384;
    f16x8 kf0 = *(const f16x8*)(Bb + kro + kc0);
    f16x8 kf1 = *(const f16x8*)(Bb + kro + kc1);
    f16x8 kf2 = *(const f16x8*)(Bb + kro + kc2);
    f16x8 kf3 = *(const f16x8*)(Bb + kro + kc3);
    f16x8 vf0 = *(const f16x8*)(Bb + vb0 + vc0);
    f16x8 vf1 = *(const f16x8*)(Bb + vb0 + vc1);
    f16x8 vf2 = *(const f16x8*)(Bb + vb1 + vc0);
    f16x8 vf3 = *(const f16x8*)(Bb + vb1 + vc1);
    if (tl < 31) STAGE(cur ^ 1, tl + 1);
    // QK^T
    f32x16 sacc = {};
    __builtin_amdgcn_s_setprio(1);
    sacc = __builtin_amdgcn_mfma_f32_32x32x16_f16(kf0, qf0, sacc, 0, 0, 0);
    sacc = __builtin_amdgcn_mfma_f32_32x32x16_f16(kf1, qf1, sacc, 0, 0, 0);
    sacc = __builtin_amdgcn_mfma_f32_32x32x16_f16(kf2, qf2, sacc, 0, 0, 0);
    sacc = __builtin_amdgcn_mfma_f32_32x32x16_f16(kf3, qf3, sacc, 0, 0, 0);
    __builtin_amdgcn_s_setprio(0);
    // softmax in-register: exp2, pack, permlane redistribute
    u32 Dw[8];
#pragma unroll
    for (int u = 0; u < 4; ++u) {
#pragma unroll
      for (int v = 0; v < 2; ++v) {
        float a  = __builtin_amdgcn_exp2f(sacc[u * 4 + v * 2]);
        float b2 = __builtin_amdgcn_exp2f(sacc[u * 4 + v * 2 + 1]);
        lsw += a + b2;
        union { fp16x2 h; u32 u; } cv;
        cv.h = __builtin_amdgcn_cvt_pkrtz(a, b2);
        Dw[u * 2 + v] = cv.u;
      }
    }
    plane_swap(Dw[0], Dw[2]);
    plane_swap(Dw[1], Dw[3]);
    plane_swap(Dw[4], Dw[6]);
    plane_swap(Dw[5], Dw[7]);
    union { f16x8 v; u32 d[4]; } p0, p1;
    p0.d[0] = Dw[0]; p0.d[1] = Dw[1]; p0.d[2] = Dw[2]; p0.d[3] = Dw[3];
    p1.d[0] = Dw[4]; p1.d[1] = Dw[5]; p1.d[2] = Dw[6]; p1.d[3] = Dw[7];
    // PV
    __builtin_amdgcn_s_setprio(1);
    oacc0 = __builtin_amdgcn_mfma_f32_32x32x16_f16(p0.v, vf0, oacc0, 0, 0, 0);
    oacc0 = __builtin_amdgcn_mfma_f32_32x32x16_f16(p1.v, vf1, oacc0, 0, 0, 0);
    oacc1 = __builtin_amdgcn_mfma_f32_32x32x16_f16(p0.v, vf2, oacc1, 0, 0, 0);
    oacc1 = __builtin_amdgcn_mfma_f32_32x32x16_f16(p1.v, vf3, oacc1, 0, 0, 0);
    __builtin_amdgcn_s_setprio(0);
    __syncthreads();
  }
#undef STAGE
  // ---- epilogue: combine 4 key-slice partials via LDS (alias of KVl) ----
  lsw += __shfl_xor(lsw, 32, 64);
  if (hi == 0) Lsh[w * 32 + r] = lsw;
#pragma unroll
  for (int dt = 0; dt < 2; ++dt) {
    f16* orow = KVl + w * 2048 + (dt * 32 + r) * 32;
    const f32x16& oa = dt ? oacc1 : oacc0;
#pragma unroll
    for (int u = 0; u < 4; ++u) {
      f16x4 h4;
      h4[0] = (f16)oa[u * 4 + 0]; h4[1] = (f16)oa[u * 4 + 1];
      h4[2] = (f16)oa[u * 4 + 2]; h4[3] = (f16)oa[u * 4 + 3];
      *(f16x4*)(orow + ((u ^ (r & 3)) * 8) + hi * 4) = h4;
    }
  }
  __syncthreads();
  // combine: wave w = (s2 q-16-group-pair, dt2 dd-half, qh2 q-half)
  const int s2 = w >> 2, dt2 = (w >> 1) & 1, qh2 = w & 1;
  const int g = s2 * 2 + hi;    // q 8-group within 32-half
  const int b = bh >> 2, h = bh & 3;
  float accv[8] = {}, denv[8] = {};
#pragma unroll
  for (int ksl = 0; ksl < 4; ++ksl) {
    const int wp = ksl * 2 + qh2;
    f16x8 rd = *(const f16x8*)(KVl + wp * 2048 + (dt2 * 32 + r) * 32 + ((g ^ (r & 3)) * 8));
    f32x4 la = *(const f32x4*)(Lsh + wp * 32 + g * 8);
    f32x4 lb = *(const f32x4*)(Lsh + wp * 32 + g * 8 + 4);
#pragma unroll
    for (int j = 0; j < 4; ++j) {
      accv[j]     += (float)rd[j];
      accv[4 + j] += (float)rd[4 + j];
      denv[j]     += la[j];
      denv[4 + j] += lb[j];
    }
  }
  const int ng = qt * 64 + qh2 * 32 + g * 8;
  const int np = (dt2 * 32 + r) * 64 + h * 16 + (ng >> 8);
  const int cp_ = ng & 255;
  f16x8 yv;
#pragma unroll
  for (int j = 0; j < 8; ++j) yv[j] = (f16)(accv[j] / denv[j]);
  *(f16x8*)(Y + ((size_t)b * 4096 + np) * 256 + cp_) = yv;
}

extern "C" void kernel_launch(void* const* d_in, const int* in_sizes, int n_in,
                              void* d_out, int out_size, void* d_ws, size_t ws_size,
                              hipStream_t stream)
{
  const float* x     = (const float*)d_in[0];   // [2,4096,256]
  const float* w_qkv = (const float*)d_in[1];   // [768,256]
  const float* w_out = (const float*)d_in[2];   // [256,256]
  const float* b_out = (const float*)d_in[3];   // [256]
  const float* temp  = (const float*)d_in[4];   // [4,1,1]

  char* ws = (char*)d_ws;
  f16*   xb    = (f16*)(ws);                                  // 4MB
  f16*   wqkvb = (f16*)(ws + 4 * 1024 * 1024);
  f16*   woutb = (f16*)(ws + 4 * 1024 * 1024 + 512 * 1024);
  f16*   Qb    = (f16*)(ws + 5  * 1024 * 1024);               // [8][4096][64]
  f16*   Kb    = (f16*)(ws + 9  * 1024 * 1024);
  f16*   Vtb   = (f16*)(ws + 13 * 1024 * 1024);               // [8][64][4096]
  float* partQ = (float*)(ws + 17 * 1024 * 1024 + 8192);      // 128KB
  float* partK = (float*)(ws + 17 * 1024 * 1024 + 8192 + 131072);
  f16*   Y     = (f16*)(ws + 18 * 1024 * 1024);               // [2][4096][256]
  float* outF  = (float*)d_out;

  k_cvt<<<2304, 256, 0, stream>>>(x, w_qkv, w_out, xb, wqkvb, woutb);
  k_gemm<<<dim3(12, 128), 256, 0, stream>>>(xb, wqkvb, 256, 0, Qb, Kb, Vtb,
                                            nullptr, nullptr, partQ, partK);
  k_flash6<<<512, 512, 0, stream>>>(Qb, Kb, Vtb, partQ, partK, temp, Y);
  k_gemm<<<dim3(4, 128), 256, 0, stream>>>(Y, woutb, 256, 1, nullptr, nullptr, nullptr,
                                           outF, b_out, nullptr, nullptr);
}